// Round 10
// baseline (282.499 us; speedup 1.0000x reference)
//
#include <hip/hip_runtime.h>

typedef unsigned short u16;
typedef unsigned int u32;
typedef __attribute__((ext_vector_type(2))) u32 u32x2;
typedef __attribute__((ext_vector_type(4))) u32 u32x4;
typedef __attribute__((ext_vector_type(8))) short bf16x8;
typedef __attribute__((ext_vector_type(4))) float f32x4;

// round-to-nearest-even fp32 -> bf16 (scalar fallback)
__device__ __forceinline__ u16 f2bf(float f) {
  u32 b = __float_as_uint(f);
  b += 0x7fffu + ((b >> 16) & 1u);
  return (u16)(b >> 16);
}

// packed fp32x2 -> bf16x2 (hardware v_cvt_pk_bf16_f32 on gfx950; RNE both ways)
__device__ __forceinline__ u32 pk2bf(float a, float b) {
#if __has_builtin(__builtin_amdgcn_cvt_pk_bf16_f32)
  return __builtin_bit_cast(u32, __builtin_amdgcn_cvt_pk_bf16_f32(a, b));
#else
  return (u32)f2bf(a) | ((u32)f2bf(b) << 16);
#endif
}

__device__ __forceinline__ bf16x8 mk_ones8() {
  u32x4 t;
  t[0] = t[1] = t[2] = t[3] = 0x3F803F80u;  // bf16 1.0 x2 per word
  return __builtin_bit_cast(bf16x8, t);
}

// 2^x via the native v_exp_f32 (which computes exp2). NOTE: __exp2f is a
// reserved glibc symbol -- do not use that name.
__device__ __forceinline__ float fexp2(float x) {
#if __has_builtin(__builtin_amdgcn_exp2f)
  return __builtin_amdgcn_exp2f(x);
#else
  return exp2f(x);
#endif
}

__device__ __forceinline__ f32x4 mfma32(bf16x8 a, bf16x8 b, f32x4 c) {
  return __builtin_amdgcn_mfma_f32_16x16x32_bf16(a, b, c, 0, 0, 0);
}

// async global->LDS, 16B/lane; LDS dst = wave-uniform base + lane*16 [m97/m104]
__device__ __forceinline__ void gload_lds16(const u16* g, u16* l) {
  __builtin_amdgcn_global_load_lds((const __attribute__((address_space(1))) void*)g,
                                   (__attribute__((address_space(3))) void*)l, 16, 0, 0);
}

// ---------------- fp32 -> bf16 convert, 3 tensors in ONE launch -------------
// regions: x 4096 blocks, W_attn 1536, W_out 512 (8 elems/thread each).
__global__ __launch_bounds__(256) void cvt_all(const float* __restrict__ x,
                                               const float* __restrict__ wa,
                                               const float* __restrict__ wo,
                                               u16* __restrict__ xb,
                                               u16* __restrict__ wab,
                                               u16* __restrict__ wob) {
  int blk = blockIdx.x;
  const float* in;
  u16* out;
  long base;
  if (blk < 4096) {
    in = x; out = xb; base = blk;
  } else if (blk < 5632) {
    in = wa; out = wab; base = blk - 4096;
  } else {
    in = wo; out = wob; base = blk - 5632;
  }
  long i = (base * 256 + threadIdx.x) * 8;
  u32 u[8];
#pragma unroll
  for (int j = 0; j < 8; j++) {
    u32 b = __float_as_uint(in[i + j]);
    u[j] = (b + 0x7fffu + ((b >> 16) & 1u)) >> 16;
  }
  u32x4 o;
  o[0] = u[0] | (u[1] << 16);
  o[1] = u[2] | (u[3] << 16);
  o[2] = u[4] | (u[5] << 16);
  o[3] = u[6] | (u[7] << 16);
  *(u32x4*)(out + i) = o;
}

// ---------------- 256x256 GEMM core (R9): K-half ring + counted vmcnt -------
// C[256x256] = A[256xK=1024] * B[256x1024]^T. 512 thr = 8 waves (2M x 4N),
// per-wave C 128x64 (acc[8][4]). LDS: 4-slot ring x (A 16KB + B 16KB) =
// 128KB; slot holds a K=32 half-tile of both panels. Staging runs 3 half-
// slots AHEAD (slot hs+3 was last read at hs-1, freed by hs's boundary
// barrier) -> the boundary wait is a COUNTED vmcnt(8): hs+1/hs+2 chunks
// (2x4 loads) stay in flight; never vmcnt(0) in the loop [T3+T4, m218].
// Per half-slot: 2 phases {issue 2 staging gloads; ds_read frags (8/4
// b128); lgkmcnt(0); setprio(1); 16 MFMA; setprio(0)} [T5]. Chunk swizzle:
// phys 8-elem chunk = quad ^ ((row>>1)&3), pre-applied to the global source
// (gload dst stays linear, rule #21); reads <=2-way banked (free) [T2].
// Tail wrap: last 3 half-slots re-stage wrapped K (harmless) so vmcnt(8)
// stays uniform.
__device__ __forceinline__ void gemm256_core(const u16* __restrict__ A,
                                             const u16* __restrict__ B,
                                             int m0, int n0, u16* As, u16* Bs,
                                             f32x4 acc[8][4]) {
  const int K = 1024;
  int t = threadIdx.x, lane = t & 63, w = t >> 6;
  int quad = lane >> 4, l16 = lane & 15;
  int wm = w >> 2, wn = w & 3;
  // staging: lane -> (row lane>>2 in a 16-row block, phys 16B slot lane&3);
  // logical chunk = phys ^ key(row), key = (row>>1)&3 -> (lane>>3)&3
  int lrow = lane >> 2;
  int lchunk = (lane & 3) ^ ((lane >> 3) & 3);
  const u16* Ag0 = A + (long)(m0 + w * 32 + lrow) * K + lchunk * 8;
  const u16* Ag1 = A + (long)(m0 + w * 32 + 16 + lrow) * K + lchunk * 8;
  const u16* Bg0 = B + (long)(n0 + w * 32 + lrow) * K + lchunk * 8;
  const u16* Bg1 = B + (long)(n0 + w * 32 + 16 + lrow) * K + lchunk * 8;
  u16* Asw0 = As + (w * 32) * 32;
  u16* Asw1 = As + (w * 32 + 16) * 32;
  u16* Bsw0 = Bs + (w * 32) * 32;
  u16* Bsw1 = Bs + (w * 32 + 16) * 32;
  // frag read lane base: row = base16 + l16, phys chunk = quad ^ ((l16>>1)&3)
  int rk = (quad ^ ((l16 >> 1) & 3)) * 8;
  const u16* aR = As + (wm * 128 + l16) * 32 + rk;  // + mf*512 + slot*8192
  const u16* bR = Bs + (wn * 64 + l16) * 32 + rk;   // + nf*512 + slot*8192

#define STG_A9(kk, ss)                                \
  do {                                                \
    gload_lds16(Ag0 + (kk), Asw0 + (ss) * 8192);      \
    gload_lds16(Ag1 + (kk), Asw1 + (ss) * 8192);      \
  } while (0)
#define STG_B9(kk, ss)                                \
  do {                                                \
    gload_lds16(Bg0 + (kk), Bsw0 + (ss) * 8192);      \
    gload_lds16(Bg1 + (kk), Bsw1 + (ss) * 8192);      \
  } while (0)

  // prologue: stage half-slots 0,1,2 into ring slots 0,1,2 (12 loads)
  STG_A9(0, 0);
  STG_B9(0, 0);
  STG_A9(32, 1);
  STG_B9(32, 1);
  STG_A9(64, 2);
  STG_B9(64, 2);

  for (int hb = 0; hb < 32; hb += 4) {
#pragma unroll
    for (int j = 0; j < 4; j++) {
      const int ss = j;                    // compute slot (compile-time)
      const int sst = (j + 3) & 3;         // staging slot (compile-time)
      int kst = ((hb + j + 3) & 31) * 32;  // staging K offset (wraps at tail)
      // ---- boundary: counted drain (hs's own chunks), raw barrier ----
      __builtin_amdgcn_sched_barrier(0);
      asm volatile("s_waitcnt vmcnt(8)" ::: "memory");
      __builtin_amdgcn_s_barrier();
      __builtin_amdgcn_sched_barrier(0);
      // ---- phase a: stage A-chunk(hs+3); frags mf0-3 x nf0-3 ----
      STG_A9(kst, sst);
      bf16x8 af[8], bfr[4];
#pragma unroll
      for (int mf = 0; mf < 4; mf++)
        af[mf] = *(const bf16x8*)(aR + ss * 8192 + mf * 512);
#pragma unroll
      for (int nf = 0; nf < 4; nf++)
        bfr[nf] = *(const bf16x8*)(bR + ss * 8192 + nf * 512);
      asm volatile("s_waitcnt lgkmcnt(0)" ::: "memory");
      __builtin_amdgcn_sched_barrier(0);
      __builtin_amdgcn_s_setprio(1);
#pragma unroll
      for (int mf = 0; mf < 4; mf++)
#pragma unroll
        for (int nf = 0; nf < 4; nf++)
          acc[mf][nf] = mfma32(af[mf], bfr[nf], acc[mf][nf]);
      __builtin_amdgcn_s_setprio(0);
      __builtin_amdgcn_sched_barrier(0);
      // ---- phase b: stage B-chunk(hs+3); frags mf4-7 (bfr reused) ----
      STG_B9(kst, sst);
#pragma unroll
      for (int mf = 4; mf < 8; mf++)
        af[mf] = *(const bf16x8*)(aR + ss * 8192 + mf * 512);
      asm volatile("s_waitcnt lgkmcnt(0)" ::: "memory");
      __builtin_amdgcn_sched_barrier(0);
      __builtin_amdgcn_s_setprio(1);
#pragma unroll
      for (int mf = 4; mf < 8; mf++)
#pragma unroll
        for (int nf = 0; nf < 4; nf++)
          acc[mf][nf] = mfma32(af[mf], bfr[nf], acc[mf][nf]);
      __builtin_amdgcn_s_setprio(0);
      __builtin_amdgcn_sched_barrier(0);
    }
  }
#undef STG_A9
#undef STG_B9
}

// ---------------- GEMM1 (256sq): kqv^T = W_attn @ x^T, scatter K/Q/Vt -------
// Epilogue = R8's swapped scatter over 8x4 fragments. which = m0>>10 is
// block-uniform (1024 % 256 == 0). Grid (32, 12) = 384 blocks.
#define QSCALE 0.1803368801f
__global__ __launch_bounds__(512, 2) void gemm_qkv(const u16* __restrict__ A,
                                                   const u16* __restrict__ B,
                                                   const float* __restrict__ bias,
                                                   u16* __restrict__ Kg,
                                                   u16* __restrict__ Qg,
                                                   u16* __restrict__ Vg) {
  __shared__ __align__(16) u16 As[4][256 * 32];  // 64KB
  __shared__ __align__(16) u16 Bs[4][256 * 32];  // 64KB
  int m0 = blockIdx.y * 256, n0 = blockIdx.x * 256;  // m=feature, n=token
  f32x4 acc[8][4];
#pragma unroll
  for (int i = 0; i < 8; i++)
#pragma unroll
    for (int j = 0; j < 4; j++) acc[i][j] = (f32x4)0.0f;
  gemm256_core(A, B, m0, n0, &As[0][0], &Bs[0][0], acc);

  int t = threadIdx.x, lane = t & 63, w = t >> 6;
  int quad = lane >> 4, l16 = lane & 15;
  int wm = w >> 2, wn = w & 3;
  int which = m0 >> 10;  // 0=K,1=Q,2=V -- uniform for the whole block
#pragma unroll
  for (int mf = 0; mf < 8; mf++) {
    int m = m0 + wm * 128 + mf * 16 + quad * 4;  // feature (r spans m..m+3)
    int h = (m >> 6) & 15, d0 = m & 63;
    f32x4 b4 = *(const f32x4*)&bias[m];
#pragma unroll
    for (int nf = 0; nf < 4; nf++) {
      int n = n0 + wn * 64 + nf * 16 + l16;  // token
      int b = n >> 11, s = n & 2047;
      long bh = (long)b * 16 + h;
      if (which == 0) {
        u32x2 pk;
        pk[0] = pk2bf(acc[mf][nf][0] + b4[0], acc[mf][nf][1] + b4[1]);
        pk[1] = pk2bf(acc[mf][nf][2] + b4[2], acc[mf][nf][3] + b4[3]);
        *(u32x2*)&Kg[(bh * 2048 + s) * 64 + d0] = pk;
      } else if (which == 1) {
        u32x2 pk;
        pk[0] = pk2bf((acc[mf][nf][0] + b4[0]) * QSCALE,
                      (acc[mf][nf][1] + b4[1]) * QSCALE);
        pk[1] = pk2bf((acc[mf][nf][2] + b4[2]) * QSCALE,
                      (acc[mf][nf][3] + b4[3]) * QSCALE);
        *(u32x2*)&Qg[(bh * 2048 + s) * 64 + d0] = pk;
      } else {
#pragma unroll
        for (int r = 0; r < 4; r++)
          Vg[(bh * 64 + d0 + r) * 2048 + s] = f2bf(acc[mf][nf][r] + b4[r]);
      }
    }
  }
}

// ---------------- shared GEMM core: C[128x128] = A[128xK] * B[128xK]^T ------
// (retained for gemm_out; R8-verbatim)
__device__ __forceinline__ void gemm_core_128(const u16* __restrict__ A,
                                              const u16* __restrict__ B, int K,
                                              int m0, int n0, u16* As, u16* Bs,
                                              f32x4 acc[4][4]) {
  int t = threadIdx.x;
  int lane = t & 63, w = t >> 6;
  int quad = lane >> 4, l16 = lane & 15;
  int wm = (w >> 1) * 64, wn = (w & 1) * 64;
  int lr = lane >> 3, lc = lane & 7;  // staging: lane -> (row-in-8, chunk slot)
  int cg = lc ^ lr;                   // swizzled global source chunk
  int swz = l16 & 7;
  for (int k0 = 0; k0 < K; k0 += 64) {
#pragma unroll
    for (int i = 0; i < 4; i++) {
      int r0 = i * 32 + w * 8;
      gload_lds16(&A[(long)(m0 + r0 + lr) * K + k0 + cg * 8], &As[r0 * 64]);
      gload_lds16(&B[(long)(n0 + r0 + lr) * K + k0 + cg * 8], &Bs[r0 * 64]);
    }
    __syncthreads();
#pragma unroll
    for (int ks = 0; ks < 2; ks++) {
      bf16x8 a[4], b[4];
#pragma unroll
      for (int tm = 0; tm < 4; tm++)
        a[tm] = *(const bf16x8*)&As[(wm + tm * 16 + l16) * 64 + ((ks * 4 + quad) ^ swz) * 8];
#pragma unroll
      for (int tn = 0; tn < 4; tn++)
        b[tn] = *(const bf16x8*)&Bs[(wn + tn * 16 + l16) * 64 + ((ks * 4 + quad) ^ swz) * 8];
#pragma unroll
      for (int tm = 0; tm < 4; tm++)
#pragma unroll
        for (int tn = 0; tn < 4; tn++)
          acc[tm][tn] = __builtin_amdgcn_mfma_f32_16x16x32_bf16(a[tm], b[tn],
                                                                acc[tm][tn], 0, 0, 0);
    }
    __syncthreads();
  }
}

// ---------------- GEMM2 (SWAPPED): out^T = W_out @ y^T (fp32 out) -----------
// Feature in regs -> out[(token)*1024 + feature] is a contiguous f32x4 store.
__global__ __launch_bounds__(256) void gemm_out(const u16* __restrict__ A,
                                                const u16* __restrict__ B,
                                                const float* __restrict__ bias,
                                                float* __restrict__ out) {
  __shared__ __align__(16) u16 As[128 * 64];
  __shared__ __align__(16) u16 Bs[128 * 64];
  const int K = 1024;
  int m0 = blockIdx.y * 128, n0 = blockIdx.x * 128;  // m=feature, n=token
  f32x4 acc[4][4];
#pragma unroll
  for (int i = 0; i < 4; i++)
#pragma unroll
    for (int j = 0; j < 4; j++) acc[i][j] = (f32x4)0.0f;
  gemm_core_128(A, B, K, m0, n0, As, Bs, acc);

  int t = threadIdx.x, lane = t & 63, w = t >> 6;
  int quad = lane >> 4, l16 = lane & 15;
  int wm = (w >> 1) * 64, wn = (w & 1) * 64;
#pragma unroll
  for (int tm = 0; tm < 4; tm++) {
    int m = m0 + wm + tm * 16 + quad * 4;  // feature
    f32x4 b4 = *(const f32x4*)&bias[m];
#pragma unroll
    for (int tn = 0; tn < 4; tn++) {
      int n = n0 + wn + tn * 16 + l16;  // token
      f32x4 o = acc[tm][tn] + b4;
      *(f32x4*)&out[(long)n * 1024 + m] = o;
    }
  }
}

// ---------------- flash attention (R8-verbatim: 8 waves, full-64kv/wave) ----
// 512 thr (8 waves x 32 q), grid (8,64) = exactly 2 blocks/CU (64KB LDS).
// P through per-wave LDS scratch with FULL 4-bit granule XOR (phys = g^l16)
// -> conflict-free writes AND reads (R8 measured: SQ_LDS_BANK_CONFLICT = 0).
// 28 MFMA/visit (8 QK K=32 + 16 PV K=32 + 4 ones-denominator).
#define SYNC                                       \
  __builtin_amdgcn_sched_barrier(0);               \
  asm volatile("s_waitcnt vmcnt(0)" ::: "memory"); \
  __builtin_amdgcn_s_barrier();                    \
  __builtin_amdgcn_sched_barrier(0)

#define STAGE_KV(tt, bb)                                      \
  do {                                                        \
    gload_lds16(Kst + (long)(tt)*4096, &Ks[bb][w * 8 * 64]);  \
    gload_lds16(Vst + (tt)*64, &Vs[bb][w * 8 * 64]);          \
  } while (0)

#define COMPUTE(bb)                                                            \
  do {                                                                         \
    bf16x8 pf_[2][2];                                                          \
    _Pragma("unroll") for (int tq = 0; tq < 2; tq++) {                         \
      f32x4 s_[4];                                                             \
      __builtin_amdgcn_s_setprio(1);                                           \
      _Pragma("unroll") for (int tn = 0; tn < 4; tn++) {                       \
        bf16x8 kf0 = *(const bf16x8*)(kL0 + (bb)*4096 + tn * 1024);            \
        bf16x8 kf1 = *(const bf16x8*)(kL1 + (bb)*4096 + tn * 1024);            \
        s_[tn] = __builtin_amdgcn_mfma_f32_16x16x32_bf16(kf0, qf[tq][0], Z,    \
                                                         0, 0, 0);             \
        s_[tn] = __builtin_amdgcn_mfma_f32_16x16x32_bf16(kf1, qf[tq][1],       \
                                                         s_[tn], 0, 0, 0);     \
      }                                                                        \
      __builtin_amdgcn_s_setprio(0);                                           \
      _Pragma("unroll") for (int tn = 0; tn < 4; tn++) {                       \
        float e0 = fexp2(s_[tn][0]);                                           \
        float e1 = fexp2(s_[tn][1]);                                           \
        float e2 = fexp2(s_[tn][2]);                                           \
        float e3 = fexp2(s_[tn][3]);                                           \
        u32x2 pk;                                                              \
        pk[0] = pk2bf(e0, e1);                                                 \
        pk[1] = pk2bf(e2, e3);                                                 \
        *(u32x2*)(pW + tq * 1024 + woff[tn]) = pk;                             \
      }                                                                        \
    }                                                                          \
    _Pragma("unroll") for (int ks = 0; ks < 2; ks++)                           \
        _Pragma("unroll") for (int tq = 0; tq < 2; tq++) {                     \
      u32x2 lo = *(const u32x2*)(pR + tq * 1024 + prlo[ks]);                   \
      u32x2 hi = *(const u32x2*)(pR + tq * 1024 + prhi[ks]);                   \
      u32x4 cc;                                                                \
      cc[0] = lo[0];                                                           \
      cc[1] = lo[1];                                                           \
      cc[2] = hi[0];                                                           \
      cc[3] = hi[1];                                                           \
      pf_[tq][ks] = __builtin_bit_cast(bf16x8, cc);                            \
    }                                                                          \
    __builtin_amdgcn_s_setprio(1);                                             \
    _Pragma("unroll") for (int ks = 0; ks < 2; ks++) {                         \
      acc_sum[0] = __builtin_amdgcn_mfma_f32_16x16x32_bf16(ONES, pf_[0][ks],   \
                                                           acc_sum[0], 0, 0, 0); \
      acc_sum[1] = __builtin_amdgcn_mfma_f32_16x16x32_bf16(ONES, pf_[1][ks],   \
                                                           acc_sum[1], 0, 0, 0); \
      _Pragma("unroll") for (int dt = 0; dt < 4; dt++) {                       \
        bf16x8 vf = *(const bf16x8*)(vL[ks] + (bb)*4096 + dt * 1024);          \
        acc[dt][0] = __builtin_amdgcn_mfma_f32_16x16x32_bf16(vf, pf_[0][ks],   \
                                                             acc[dt][0], 0, 0, 0); \
        acc[dt][1] = __builtin_amdgcn_mfma_f32_16x16x32_bf16(vf, pf_[1][ks],   \
                                                             acc[dt][1], 0, 0, 0); \
      }                                                                        \
    }                                                                          \
    __builtin_amdgcn_s_setprio(0);                                             \
  } while (0)

__global__ __launch_bounds__(512, 4) void attn_kernel(const u16* __restrict__ Qg,
                                                      const u16* __restrict__ Kg,
                                                      const u16* __restrict__ Vg,
                                                      u16* __restrict__ Y) {
  __shared__ __align__(16) u16 Ks[2][64 * 64];     // [buf][kv][d] XOR-swizzled
  __shared__ __align__(16) u16 Vs[2][64 * 64];     // [buf][d][kv] XOR-swizzled
  __shared__ __align__(16) u16 Ps[8 * 32 * 64];    // per-wave [q][kv] granule-swz
  int t = threadIdx.x, lane = t & 63, w = t >> 6;  // 8 waves
  int quad = lane >> 4, l16 = lane & 15;
  int bh = blockIdx.y;
  int q0 = blockIdx.x * 256 + w * 32;
  int lr = lane >> 3, lc = lane & 7, cg = lc ^ lr;
  int swz = l16 & 7;
  u16* Pw = Ps + w * 2048;

  // Q fragments (MFMA B-operand), loaded once: qf[tq][ks]
  bf16x8 qf[2][2];
#pragma unroll
  for (int tq = 0; tq < 2; tq++) {
    const u16* qp = Qg + ((long)bh * 2048 + q0 + tq * 16 + l16) * 64;
    qf[tq][0] = *(const bf16x8*)(qp + quad * 8);
    qf[tq][1] = *(const bf16x8*)(qp + 32 + quad * 8);
  }

  const f32x4 Z = {0.0f, 0.0f, 0.0f, 0.0f};  // hoisted zero C-operand
  const bf16x8 ONES = mk_ones8();            // bf16 1.0 x8 (denominator MFMA)

  f32x4 acc[4][2];   // [dt d][tq q]  out^T: row=d, col=q
  f32x4 acc_sum[2];  // softmax denominators via ones-MFMA (all rows equal)
#pragma unroll
  for (int dt = 0; dt < 4; dt++)
#pragma unroll
    for (int tq = 0; tq < 2; tq++) acc[dt][tq] = (f32x4)0.0f;
  acc_sum[0] = (f32x4)0.0f;
  acc_sum[1] = (f32x4)0.0f;

  // loop-invariant LDS lane pointers (compile-time immediates added per use)
  const u16* kL0 = &Ks[0][l16 * 64 + (quad ^ swz) * 8];        // ks=0 chunk
  const u16* kL1 = &Ks[0][l16 * 64 + ((4 + quad) ^ swz) * 8];  // ks=1 chunk
  const u16* vL[2] = {&Vs[0][l16 * 64 + (quad ^ swz) * 8],
                      &Vs[0][l16 * 64 + ((4 + quad) ^ swz) * 8]};
  u16* pW = Pw + l16 * 64;
  const u16* pR = Pw + l16 * 64;
  // P granule swizzle: 8B granule g_phys = g_log ^ l16 (full 4-bit row key)
  int woff[4], prlo[2], prhi[2];
#pragma unroll
  for (int tn = 0; tn < 4; tn++) woff[tn] = ((tn * 4 + quad) ^ l16) * 4;
#pragma unroll
  for (int ks = 0; ks < 2; ks++) {
    prlo[ks] = ((ks * 8 + quad * 2) ^ l16) * 4;
    prhi[ks] = ((ks * 8 + quad * 2 + 1) ^ l16) * 4;
  }

  // staging base pointers: wave w stages rows w*8..w*8+7 of each tile
  const u16* Kst = Kg + ((long)bh * 2048 + w * 8 + lr) * 64 + cg * 8;   // +tt*4096
  const u16* Vst = Vg + ((long)(bh * 64 + w * 8 + lr)) * 2048 + cg * 8; // +tt*64

  STAGE_KV(0, 0);
  for (int tt = 0; tt < 30; tt += 2) {
    SYNC;
    STAGE_KV(tt + 1, 1);
    COMPUTE(0);
    SYNC;
    STAGE_KV(tt + 2, 0);
    COMPUTE(1);
  }
  SYNC;
  STAGE_KV(31, 1);
  COMPUTE(0);
  SYNC;
  COMPUTE(1);

  // epilogue: out^T row=d=dt*16+quad*4+r, col=q=tq*16+l16.
  // acc_sum rows all identical (ones-A) => full denominator in every reg.
  int b = bh >> 4, h = bh & 15;
#pragma unroll
  for (int tq = 0; tq < 2; tq++) {
    float inv = 1.0f / acc_sum[tq][0];
    long row = (long)b * 2048 + q0 + tq * 16 + l16;
#pragma unroll
    for (int dt = 0; dt < 4; dt++) {
      u32x2 pk;
      pk[0] = pk2bf(acc[dt][tq][0] * inv, acc[dt][tq][1] * inv);
      pk[1] = pk2bf(acc[dt][tq][2] * inv, acc[dt][tq][3] * inv);
      *(u32x2*)&Y[row * 1024 + h * 64 + dt * 16 + quad * 4] = pk;
    }
  }
}

// ---------------- launch ----------------------------------------------------
extern "C" void kernel_launch(void* const* d_in, const int* in_sizes, int n_in,
                              void* d_out, int out_size, void* d_ws, size_t ws_size,
                              hipStream_t stream) {
  const float* x = (const float*)d_in[0];       // (4,2048,1024)
  const float* W_attn = (const float*)d_in[1];  // (3072,1024)
  const float* b_attn = (const float*)d_in[2];  // (3072,)
  const float* W_out = (const float*)d_in[3];   // (1024,1024)
  const float* b_out = (const float*)d_in[4];   // (1024,)
  float* out = (float*)d_out;                   // (4,2048,1024) fp32

  char* ws = (char*)d_ws;
  u16* xb = (u16*)ws;                             // 8192*1024 bf16 = 16 MB
  u16* Wab = (u16*)(ws + 16777216);               // 3072*1024 = 6 MB
  u16* Wob = (u16*)(ws + 16777216 + 6291456);     // 1024*1024 = 2 MB
  u16* Kg = (u16*)(ws + 25165824);                // (b,h,s,d) 16 MB
  u16* Qg = Kg + 8388608;                         // (b,h,s,d) pre-scaled 16 MB
  u16* Vg = Qg + 8388608;                         // (b,h,d,s) 16 MB
  u16* Yb = xb;  // alias: x no longer needed after GEMM1

  cvt_all<<<6144, 256, 0, stream>>>(x, W_attn, W_out, xb, Wab, Wob);

  // SWAPPED gemms: A = weights (feature rows), B = activations (token rows)
  gemm_qkv<<<dim3(32, 12), 512, 0, stream>>>(Wab, xb, b_attn, Kg, Qg, Vg);
  attn_kernel<<<dim3(8, 64), 512, 0, stream>>>(Qg, Kg, Vg, Yb);
  gemm_out<<<dim3(64, 8), 256, 0, stream>>>(Wob, Yb, b_out, out);
}

// Round 11
// 274.064 us; speedup vs baseline: 1.0308x; 1.0308x over previous
//
#include <hip/hip_runtime.h>

typedef unsigned short u16;
typedef unsigned int u32;
typedef __attribute__((ext_vector_type(2))) u32 u32x2;
typedef __attribute__((ext_vector_type(4))) u32 u32x4;
typedef __attribute__((ext_vector_type(8))) short bf16x8;
typedef __attribute__((ext_vector_type(4))) float f32x4;

// round-to-nearest-even fp32 -> bf16 (scalar fallback)
__device__ __forceinline__ u16 f2bf(float f) {
  u32 b = __float_as_uint(f);
  b += 0x7fffu + ((b >> 16) & 1u);
  return (u16)(b >> 16);
}

// packed fp32x2 -> bf16x2 (hardware v_cvt_pk_bf16_f32 on gfx950; RNE both ways)
__device__ __forceinline__ u32 pk2bf(float a, float b) {
#if __has_builtin(__builtin_amdgcn_cvt_pk_bf16_f32)
  return __builtin_bit_cast(u32, __builtin_amdgcn_cvt_pk_bf16_f32(a, b));
#else
  return (u32)f2bf(a) | ((u32)f2bf(b) << 16);
#endif
}

__device__ __forceinline__ bf16x8 mk_ones8() {
  u32x4 t;
  t[0] = t[1] = t[2] = t[3] = 0x3F803F80u;  // bf16 1.0 x2 per word
  return __builtin_bit_cast(bf16x8, t);
}

// 2^x via the native v_exp_f32 (which computes exp2). NOTE: __exp2f is a
// reserved glibc symbol -- do not use that name.
__device__ __forceinline__ float fexp2(float x) {
#if __has_builtin(__builtin_amdgcn_exp2f)
  return __builtin_amdgcn_exp2f(x);
#else
  return exp2f(x);
#endif
}

__device__ __forceinline__ f32x4 mfma32(bf16x8 a, bf16x8 b, f32x4 c) {
  return __builtin_amdgcn_mfma_f32_16x16x32_bf16(a, b, c, 0, 0, 0);
}

// async global->LDS, 16B/lane; LDS dst = wave-uniform base + lane*16 [m97/m104]
__device__ __forceinline__ void gload_lds16(const u16* g, u16* l) {
  __builtin_amdgcn_global_load_lds((const __attribute__((address_space(1))) void*)g,
                                   (__attribute__((address_space(3))) void*)l, 16, 0, 0);
}

// ---------------- fp32 -> bf16 convert, 3 tensors in ONE launch -------------
// regions: x 4096 blocks, W_attn 1536, W_out 512 (8 elems/thread each).
__global__ __launch_bounds__(256) void cvt_all(const float* __restrict__ x,
                                               const float* __restrict__ wa,
                                               const float* __restrict__ wo,
                                               u16* __restrict__ xb,
                                               u16* __restrict__ wab,
                                               u16* __restrict__ wob) {
  int blk = blockIdx.x;
  const float* in;
  u16* out;
  long base;
  if (blk < 4096) {
    in = x; out = xb; base = blk;
  } else if (blk < 5632) {
    in = wa; out = wab; base = blk - 4096;
  } else {
    in = wo; out = wob; base = blk - 5632;
  }
  long i = (base * 256 + threadIdx.x) * 8;
  u32 u[8];
#pragma unroll
  for (int j = 0; j < 8; j++) {
    u32 b = __float_as_uint(in[i + j]);
    u[j] = (b + 0x7fffu + ((b >> 16) & 1u)) >> 16;
  }
  u32x4 o;
  o[0] = u[0] | (u[1] << 16);
  o[1] = u[2] | (u[3] << 16);
  o[2] = u[4] | (u[5] << 16);
  o[3] = u[6] | (u[7] << 16);
  *(u32x4*)(out + i) = o;
}

// ---------------- 128x128 GEMM core, 3-slot K=32 ring (R11) -----------------
// R10 post-mortem: the 256sq port was NEUTRAL -- 128KB LDS forced 1 block/CU
// (384 blocks = 1.5 dispatch rounds, 33% tail; no independent block to cover
// boundary stalls). R11 keeps the counted-vmcnt ring but re-geometries:
// 128x128 tile, 256 thr (4 waves), 3-slot ring of K=32 half-tiles
// (A 8KB + B 8KB per slot) = 48KB LDS -> 3 blocks/CU, 12 waves/CU.
// qkv grid 1536 / 768 resident = EXACTLY 2.0 balanced rounds; out grid 512
// = balanced 2/CU. Ring ledger: prologue stages hs 0,1; iter j stages hs j+2
// into slot (j+2)%3; at boundary B(j) outstanding = stage(j) [oldest, 4] +
// stage(j+1) [4] -> vmcnt(4) drains stage(j) only, stage(j+1) stays in
// flight [T4]. Wrapped tail staging keeps the count uniform; one vmcnt(0)
// after the loop so no DMA outlives the block. WAR safe: stage(j+2) writes
// slot last read by compute(j-1), sealed by B(j). Chunk swizzle [T2]: LDS
// phys 8-elem chunk p at row r holds logical chunk p ^ ((r>>1)&3); staging
// pre-swizzles the global source (lchunk = (lane&3)^((lane>>3)&3), key
// invariant to 16-aligned row base); frag reads (phys = quad ^ ((l16>>1)&3))
// are <=2-way banked (free, m136). setprio(1) around MFMA [T5].
__device__ __forceinline__ void gemm_core_r3(const u16* __restrict__ A,
                                             const u16* __restrict__ B,
                                             int m0, int n0, u16* lds,
                                             f32x4 acc[4][4]) {
  const int K = 1024;
  int t = threadIdx.x, lane = t & 63, w = t >> 6;  // 4 waves
  int quad = lane >> 4, l16 = lane & 15;
  int wm = (w >> 1) * 64, wn = (w & 1) * 64;
  // staging: lane -> row' = lane>>2 (16 rows/gload), phys chunk = lane&3
  int lrow = lane >> 2;
  int lchunk = (lane & 3) ^ ((lane >> 3) & 3);  // pre-swizzled source chunk
  const u16* Ag0 = A + (long)(m0 + w * 16 + lrow) * K + lchunk * 8;
  const u16* Ag1 = A + (long)(m0 + 64 + w * 16 + lrow) * K + lchunk * 8;
  const u16* Bg0 = B + (long)(n0 + w * 16 + lrow) * K + lchunk * 8;
  const u16* Bg1 = B + (long)(n0 + 64 + w * 16 + lrow) * K + lchunk * 8;
  u16* Ad0 = lds + (w * 16) * 32;          // slot-local A rows w*16..+15
  u16* Ad1 = lds + (64 + w * 16) * 32;     // A rows 64+w*16..+15
  u16* Bd0 = lds + 4096 + (w * 16) * 32;   // B half at +8KB
  u16* Bd1 = lds + 4096 + (64 + w * 16) * 32;
  // frag read bases: row = wm/wn + tf*16 + l16, phys chunk = quad ^ key(l16)
  int rk = (quad ^ ((l16 >> 1) & 3)) * 8;
  const u16* aR = lds + (wm + l16) * 32 + rk;         // + tm*512 + slot*8192
  const u16* bR = lds + 4096 + (wn + l16) * 32 + rk;  // + tn*512 + slot*8192

#define STG_R3(kk, ss)                            \
  do {                                            \
    gload_lds16(Ag0 + (kk), Ad0 + (ss) * 8192);   \
    gload_lds16(Ag1 + (kk), Ad1 + (ss) * 8192);   \
    gload_lds16(Bg0 + (kk), Bd0 + (ss) * 8192);   \
    gload_lds16(Bg1 + (kk), Bd1 + (ss) * 8192);   \
  } while (0)

#define BOUND_R3                                     \
  __builtin_amdgcn_sched_barrier(0);                 \
  asm volatile("s_waitcnt vmcnt(4)" ::: "memory");   \
  __builtin_amdgcn_s_barrier();                      \
  __builtin_amdgcn_sched_barrier(0)

#define CMP_R3(ss)                                                   \
  do {                                                               \
    bf16x8 a_[4], b_[4];                                             \
    _Pragma("unroll") for (int tm = 0; tm < 4; tm++)                 \
        a_[tm] = *(const bf16x8*)(aR + (ss) * 8192 + tm * 512);      \
    _Pragma("unroll") for (int tn = 0; tn < 4; tn++)                 \
        b_[tn] = *(const bf16x8*)(bR + (ss) * 8192 + tn * 512);      \
    asm volatile("s_waitcnt lgkmcnt(0)" ::: "memory");               \
    __builtin_amdgcn_sched_barrier(0);                               \
    __builtin_amdgcn_s_setprio(1);                                   \
    _Pragma("unroll") for (int tm = 0; tm < 4; tm++)                 \
        _Pragma("unroll") for (int tn = 0; tn < 4; tn++)             \
            acc[tm][tn] = mfma32(a_[tm], b_[tn], acc[tm][tn]);       \
    __builtin_amdgcn_s_setprio(0);                                   \
    __builtin_amdgcn_sched_barrier(0);                               \
  } while (0)

  // prologue: half-slots 0,1 -> ring slots 0,1
  STG_R3(0, 0);
  STG_R3(32, 1);
  // 30 half-slots, x3 unrolled for compile-time slot indices
  for (int hb = 0; hb < 30; hb += 3) {
    BOUND_R3;
    STG_R3(((hb + 2) & 31) * 32, 2);
    CMP_R3(0);
    BOUND_R3;
    STG_R3(((hb + 3) & 31) * 32, 0);
    CMP_R3(1);
    BOUND_R3;
    STG_R3(((hb + 4) & 31) * 32, 1);
    CMP_R3(2);
  }
  // j=30: stage wrapped hs 0 into slot 2 (dead data, keeps vmcnt uniform)
  BOUND_R3;
  STG_R3(0, 2);
  CMP_R3(0);
  // j=31
  BOUND_R3;
  CMP_R3(1);
  // drain the wrapped staging before block exit (LDS dealloc safety)
  asm volatile("s_waitcnt vmcnt(0)" ::: "memory");
#undef STG_R3
#undef BOUND_R3
#undef CMP_R3
}

// ---------------- GEMM1 (SWAPPED): kqv^T = W_attn @ x^T, scatter K/Q/Vt -----
// Epilogue R8-verbatim: feature dim in the register (r) axis; K/Q stores one
// u32x2 per fragment; bias f32x4 vector load; which branch block-uniform.
#define QSCALE 0.1803368801f
__global__ __launch_bounds__(256, 3) void gemm_qkv(const u16* __restrict__ A,
                                                   const u16* __restrict__ B,
                                                   const float* __restrict__ bias,
                                                   u16* __restrict__ Kg,
                                                   u16* __restrict__ Qg,
                                                   u16* __restrict__ Vg) {
  __shared__ __align__(16) u16 ring[3 * 8192];  // 48KB: 3 x (A 8KB | B 8KB)
  int m0 = blockIdx.y * 128, n0 = blockIdx.x * 128;  // m=feature, n=token
  f32x4 acc[4][4];
#pragma unroll
  for (int i = 0; i < 4; i++)
#pragma unroll
    for (int j = 0; j < 4; j++) acc[i][j] = (f32x4)0.0f;
  gemm_core_r3(A, B, m0, n0, ring, acc);

  int t = threadIdx.x, lane = t & 63, w = t >> 6;
  int quad = lane >> 4, l16 = lane & 15;
  int wm = (w >> 1) * 64, wn = (w & 1) * 64;
  int which = m0 >> 10;  // 0=K,1=Q,2=V -- uniform for the whole block
#pragma unroll
  for (int tm = 0; tm < 4; tm++) {
    int m = m0 + wm + tm * 16 + quad * 4;  // feature e (r spans m..m+3)
    int h = (m >> 6) & 15, d0 = m & 63;
    f32x4 b4 = *(const f32x4*)&bias[m];
#pragma unroll
    for (int tn = 0; tn < 4; tn++) {
      int n = n0 + wn + tn * 16 + l16;  // token
      int b = n >> 11, s = n & 2047;
      long bh = (long)b * 16 + h;
      if (which == 0) {
        u32x2 pk;
        pk[0] = pk2bf(acc[tm][tn][0] + b4[0], acc[tm][tn][1] + b4[1]);
        pk[1] = pk2bf(acc[tm][tn][2] + b4[2], acc[tm][tn][3] + b4[3]);
        *(u32x2*)&Kg[(bh * 2048 + s) * 64 + d0] = pk;
      } else if (which == 1) {
        u32x2 pk;
        pk[0] = pk2bf((acc[tm][tn][0] + b4[0]) * QSCALE,
                      (acc[tm][tn][1] + b4[1]) * QSCALE);
        pk[1] = pk2bf((acc[tm][tn][2] + b4[2]) * QSCALE,
                      (acc[tm][tn][3] + b4[3]) * QSCALE);
        *(u32x2*)&Qg[(bh * 2048 + s) * 64 + d0] = pk;
      } else {
#pragma unroll
        for (int r = 0; r < 4; r++)
          Vg[(bh * 64 + d0 + r) * 2048 + s] = f2bf(acc[tm][tn][r] + b4[r]);
      }
    }
  }
}

// ---------------- GEMM2 (SWAPPED): out^T = W_out @ y^T (fp32 out) -----------
// Feature in regs -> out[(token)*1024 + feature] is a contiguous f32x4 store.
__global__ __launch_bounds__(256, 3) void gemm_out(const u16* __restrict__ A,
                                                   const u16* __restrict__ B,
                                                   const float* __restrict__ bias,
                                                   float* __restrict__ out) {
  __shared__ __align__(16) u16 ring[3 * 8192];  // 48KB
  int m0 = blockIdx.y * 128, n0 = blockIdx.x * 128;  // m=feature, n=token
  f32x4 acc[4][4];
#pragma unroll
  for (int i = 0; i < 4; i++)
#pragma unroll
    for (int j = 0; j < 4; j++) acc[i][j] = (f32x4)0.0f;
  gemm_core_r3(A, B, m0, n0, ring, acc);

  int t = threadIdx.x, lane = t & 63, w = t >> 6;
  int quad = lane >> 4, l16 = lane & 15;
  int wm = (w >> 1) * 64, wn = (w & 1) * 64;
#pragma unroll
  for (int tm = 0; tm < 4; tm++) {
    int m = m0 + wm + tm * 16 + quad * 4;  // feature
    f32x4 b4 = *(const f32x4*)&bias[m];
#pragma unroll
    for (int tn = 0; tn < 4; tn++) {
      int n = n0 + wn + tn * 16 + l16;  // token
      f32x4 o = acc[tm][tn] + b4;
      *(f32x4*)&out[(long)n * 1024 + m] = o;
    }
  }
}

// ---------------- flash attention (R8-verbatim: 8 waves, full-64kv/wave) ----
// 512 thr (8 waves x 32 q), grid (8,64) = exactly 2 blocks/CU (64KB LDS).
// P through per-wave LDS scratch with FULL 4-bit granule XOR (phys = g^l16)
// -> conflict-free writes AND reads (R8 measured: SQ_LDS_BANK_CONFLICT = 0).
// 28 MFMA/visit (8 QK K=32 + 16 PV K=32 + 4 ones-denominator).
#define SYNC                                       \
  __builtin_amdgcn_sched_barrier(0);               \
  asm volatile("s_waitcnt vmcnt(0)" ::: "memory"); \
  __builtin_amdgcn_s_barrier();                    \
  __builtin_amdgcn_sched_barrier(0)

#define STAGE_KV(tt, bb)                                      \
  do {                                                        \
    gload_lds16(Kst + (long)(tt)*4096, &Ks[bb][w * 8 * 64]);  \
    gload_lds16(Vst + (tt)*64, &Vs[bb][w * 8 * 64]);          \
  } while (0)

#define COMPUTE(bb)                                                            \
  do {                                                                         \
    bf16x8 pf_[2][2];                                                          \
    _Pragma("unroll") for (int tq = 0; tq < 2; tq++) {                         \
      f32x4 s_[4];                                                             \
      __builtin_amdgcn_s_setprio(1);                                           \
      _Pragma("unroll") for (int tn = 0; tn < 4; tn++) {                       \
        bf16x8 kf0 = *(const bf16x8*)(kL0 + (bb)*4096 + tn * 1024);            \
        bf16x8 kf1 = *(const bf16x8*)(kL1 + (bb)*4096 + tn * 1024);            \
        s_[tn] = __builtin_amdgcn_mfma_f32_16x16x32_bf16(kf0, qf[tq][0], Z,    \
                                                         0, 0, 0);             \
        s_[tn] = __builtin_amdgcn_mfma_f32_16x16x32_bf16(kf1, qf[tq][1],       \
                                                         s_[tn], 0, 0, 0);     \
      }                                                                        \
      __builtin_amdgcn_s_setprio(0);                                           \
      _Pragma("unroll") for (int tn = 0; tn < 4; tn++) {                       \
        float e0 = fexp2(s_[tn][0]);                                           \
        float e1 = fexp2(s_[tn][1]);                                           \
        float e2 = fexp2(s_[tn][2]);                                           \
        float e3 = fexp2(s_[tn][3]);                                           \
        u32x2 pk;                                                              \
        pk[0] = pk2bf(e0, e1);                                                 \
        pk[1] = pk2bf(e2, e3);                                                 \
        *(u32x2*)(pW + tq * 1024 + woff[tn]) = pk;                             \
      }                                                                        \
    }                                                                          \
    _Pragma("unroll") for (int ks = 0; ks < 2; ks++)                           \
        _Pragma("unroll") for (int tq = 0; tq < 2; tq++) {                     \
      u32x2 lo = *(const u32x2*)(pR + tq * 1024 + prlo[ks]);                   \
      u32x2 hi = *(const u32x2*)(pR + tq * 1024 + prhi[ks]);                   \
      u32x4 cc;                                                                \
      cc[0] = lo[0];                                                           \
      cc[1] = lo[1];                                                           \
      cc[2] = hi[0];                                                           \
      cc[3] = hi[1];                                                           \
      pf_[tq][ks] = __builtin_bit_cast(bf16x8, cc);                            \
    }                                                                          \
    __builtin_amdgcn_s_setprio(1);                                             \
    _Pragma("unroll") for (int ks = 0; ks < 2; ks++) {                         \
      acc_sum[0] = __builtin_amdgcn_mfma_f32_16x16x32_bf16(ONES, pf_[0][ks],   \
                                                           acc_sum[0], 0, 0, 0); \
      acc_sum[1] = __builtin_amdgcn_mfma_f32_16x16x32_bf16(ONES, pf_[1][ks],   \
                                                           acc_sum[1], 0, 0, 0); \
      _Pragma("unroll") for (int dt = 0; dt < 4; dt++) {                       \
        bf16x8 vf = *(const bf16x8*)(vL[ks] + (bb)*4096 + dt * 1024);          \
        acc[dt][0] = __builtin_amdgcn_mfma_f32_16x16x32_bf16(vf, pf_[0][ks],   \
                                                             acc[dt][0], 0, 0, 0); \
        acc[dt][1] = __builtin_amdgcn_mfma_f32_16x16x32_bf16(vf, pf_[1][ks],   \
                                                             acc[dt][1], 0, 0, 0); \
      }                                                                        \
    }                                                                          \
    __builtin_amdgcn_s_setprio(0);                                             \
  } while (0)

__global__ __launch_bounds__(512, 4) void attn_kernel(const u16* __restrict__ Qg,
                                                      const u16* __restrict__ Kg,
                                                      const u16* __restrict__ Vg,
                                                      u16* __restrict__ Y) {
  __shared__ __align__(16) u16 Ks[2][64 * 64];     // [buf][kv][d] XOR-swizzled
  __shared__ __align__(16) u16 Vs[2][64 * 64];     // [buf][d][kv] XOR-swizzled
  __shared__ __align__(16) u16 Ps[8 * 32 * 64];    // per-wave [q][kv] granule-swz
  int t = threadIdx.x, lane = t & 63, w = t >> 6;  // 8 waves
  int quad = lane >> 4, l16 = lane & 15;
  int bh = blockIdx.y;
  int q0 = blockIdx.x * 256 + w * 32;
  int lr = lane >> 3, lc = lane & 7, cg = lc ^ lr;
  int swz = l16 & 7;
  u16* Pw = Ps + w * 2048;

  // Q fragments (MFMA B-operand), loaded once: qf[tq][ks]
  bf16x8 qf[2][2];
#pragma unroll
  for (int tq = 0; tq < 2; tq++) {
    const u16* qp = Qg + ((long)bh * 2048 + q0 + tq * 16 + l16) * 64;
    qf[tq][0] = *(const bf16x8*)(qp + quad * 8);
    qf[tq][1] = *(const bf16x8*)(qp + 32 + quad * 8);
  }

  const f32x4 Z = {0.0f, 0.0f, 0.0f, 0.0f};  // hoisted zero C-operand
  const bf16x8 ONES = mk_ones8();            // bf16 1.0 x8 (denominator MFMA)

  f32x4 acc[4][2];   // [dt d][tq q]  out^T: row=d, col=q
  f32x4 acc_sum[2];  // softmax denominators via ones-MFMA (all rows equal)
#pragma unroll
  for (int dt = 0; dt < 4; dt++)
#pragma unroll
    for (int tq = 0; tq < 2; tq++) acc[dt][tq] = (f32x4)0.0f;
  acc_sum[0] = (f32x4)0.0f;
  acc_sum[1] = (f32x4)0.0f;

  // loop-invariant LDS lane pointers (compile-time immediates added per use)
  const u16* kL0 = &Ks[0][l16 * 64 + (quad ^ swz) * 8];        // ks=0 chunk
  const u16* kL1 = &Ks[0][l16 * 64 + ((4 + quad) ^ swz) * 8];  // ks=1 chunk
  const u16* vL[2] = {&Vs[0][l16 * 64 + (quad ^ swz) * 8],
                      &Vs[0][l16 * 64 + ((4 + quad) ^ swz) * 8]};
  u16* pW = Pw + l16 * 64;
  const u16* pR = Pw + l16 * 64;
  // P granule swizzle: 8B granule g_phys = g_log ^ l16 (full 4-bit row key)
  int woff[4], prlo[2], prhi[2];
#pragma unroll
  for (int tn = 0; tn < 4; tn++) woff[tn] = ((tn * 4 + quad) ^ l16) * 4;
#pragma unroll
  for (int ks = 0; ks < 2; ks++) {
    prlo[ks] = ((ks * 8 + quad * 2) ^ l16) * 4;
    prhi[ks] = ((ks * 8 + quad * 2 + 1) ^ l16) * 4;
  }

  // staging base pointers: wave w stages rows w*8..w*8+7 of each tile
  const u16* Kst = Kg + ((long)bh * 2048 + w * 8 + lr) * 64 + cg * 8;   // +tt*4096
  const u16* Vst = Vg + ((long)(bh * 64 + w * 8 + lr)) * 2048 + cg * 8; // +tt*64

  STAGE_KV(0, 0);
  for (int tt = 0; tt < 30; tt += 2) {
    SYNC;
    STAGE_KV(tt + 1, 1);
    COMPUTE(0);
    SYNC;
    STAGE_KV(tt + 2, 0);
    COMPUTE(1);
  }
  SYNC;
  STAGE_KV(31, 1);
  COMPUTE(0);
  SYNC;
  COMPUTE(1);

  // epilogue: out^T row=d=dt*16+quad*4+r, col=q=tq*16+l16.
  // acc_sum rows all identical (ones-A) => full denominator in every reg.
  int b = bh >> 4, h = bh & 15;
#pragma unroll
  for (int tq = 0; tq < 2; tq++) {
    float inv = 1.0f / acc_sum[tq][0];
    long row = (long)b * 2048 + q0 + tq * 16 + l16;
#pragma unroll
    for (int dt = 0; dt < 4; dt++) {
      u32x2 pk;
      pk[0] = pk2bf(acc[dt][tq][0] * inv, acc[dt][tq][1] * inv);
      pk[1] = pk2bf(acc[dt][tq][2] * inv, acc[dt][tq][3] * inv);
      *(u32x2*)&Y[row * 1024 + h * 64 + dt * 16 + quad * 4] = pk;
    }
  }
}

// ---------------- launch ----------------------------------------------------
extern "C" void kernel_launch(void* const* d_in, const int* in_sizes, int n_in,
                              void* d_out, int out_size, void* d_ws, size_t ws_size,
                              hipStream_t stream) {
  const float* x = (const float*)d_in[0];       // (4,2048,1024)
  const float* W_attn = (const float*)d_in[1];  // (3072,1024)
  const float* b_attn = (const float*)d_in[2];  // (3072,)
  const float* W_out = (const float*)d_in[3];   // (1024,1024)
  const float* b_out = (const float*)d_in[4];   // (1024,)
  float* out = (float*)d_out;                   // (4,2048,1024) fp32

  char* ws = (char*)d_ws;
  u16* xb = (u16*)ws;                             // 8192*1024 bf16 = 16 MB
  u16* Wab = (u16*)(ws + 16777216);               // 3072*1024 = 6 MB
  u16* Wob = (u16*)(ws + 16777216 + 6291456);     // 1024*1024 = 2 MB
  u16* Kg = (u16*)(ws + 25165824);                // (b,h,s,d) 16 MB
  u16* Qg = Kg + 8388608;                         // (b,h,s,d) pre-scaled 16 MB
  u16* Vg = Qg + 8388608;                         // (b,h,d,s) 16 MB
  u16* Yb = xb;  // alias: x no longer needed after GEMM1

  cvt_all<<<6144, 256, 0, stream>>>(x, W_attn, W_out, xb, Wab, Wob);

  // SWAPPED gemms: A = weights (feature rows), B = activations (token rows)
  gemm_qkv<<<dim3(64, 24), 256, 0, stream>>>(Wab, xb, b_attn, Kg, Qg, Vg);
  attn_kernel<<<dim3(8, 64), 512, 0, stream>>>(Qg, Kg, Vg, Yb);
  gemm_out<<<dim3(64, 8), 256, 0, stream>>>(Wob, Yb, b_out, out);
}

// Round 13
// 269.160 us; speedup vs baseline: 1.0496x; 1.0182x over previous
//
#include <hip/hip_runtime.h>

typedef unsigned short u16;
typedef unsigned int u32;
typedef __attribute__((ext_vector_type(2))) u32 u32x2;
typedef __attribute__((ext_vector_type(4))) u32 u32x4;
typedef __attribute__((ext_vector_type(8))) short bf16x8;
typedef __attribute__((ext_vector_type(4))) float f32x4;

// round-to-nearest-even fp32 -> bf16 (scalar fallback)
__device__ __forceinline__ u16 f2bf(float f) {
  u32 b = __float_as_uint(f);
  b += 0x7fffu + ((b >> 16) & 1u);
  return (u16)(b >> 16);
}

// packed fp32x2 -> bf16x2 (hardware v_cvt_pk_bf16_f32 on gfx950; RNE both ways)
__device__ __forceinline__ u32 pk2bf(float a, float b) {
#if __has_builtin(__builtin_amdgcn_cvt_pk_bf16_f32)
  return __builtin_bit_cast(u32, __builtin_amdgcn_cvt_pk_bf16_f32(a, b));
#else
  return (u32)f2bf(a) | ((u32)f2bf(b) << 16);
#endif
}

__device__ __forceinline__ bf16x8 mk_ones8() {
  u32x4 t;
  t[0] = t[1] = t[2] = t[3] = 0x3F803F80u;  // bf16 1.0 x2 per word
  return __builtin_bit_cast(bf16x8, t);
}

// 2^x via the native v_exp_f32 (which computes exp2). NOTE: __exp2f is a
// reserved glibc symbol -- do not use that name.
__device__ __forceinline__ float fexp2(float x) {
#if __has_builtin(__builtin_amdgcn_exp2f)
  return __builtin_amdgcn_exp2f(x);
#else
  return exp2f(x);
#endif
}

__device__ __forceinline__ f32x4 mfma32(bf16x8 a, bf16x8 b, f32x4 c) {
  return __builtin_amdgcn_mfma_f32_16x16x32_bf16(a, b, c, 0, 0, 0);
}

// async global->LDS, 16B/lane; LDS dst = wave-uniform base + lane*16 [m97/m104]
__device__ __forceinline__ void gload_lds16(const u16* g, u16* l) {
  __builtin_amdgcn_global_load_lds((const __attribute__((address_space(1))) void*)g,
                                   (__attribute__((address_space(3))) void*)l, 16, 0, 0);
}

// ---------------- fp32 -> bf16 convert, 3 tensors in ONE launch -------------
// regions: x 4096 blocks, W_attn 1536, W_out 512 (8 elems/thread each).
__global__ __launch_bounds__(256) void cvt_all(const float* __restrict__ x,
                                               const float* __restrict__ wa,
                                               const float* __restrict__ wo,
                                               u16* __restrict__ xb,
                                               u16* __restrict__ wab,
                                               u16* __restrict__ wob) {
  int blk = blockIdx.x;
  const float* in;
  u16* out;
  long base;
  if (blk < 4096) {
    in = x; out = xb; base = blk;
  } else if (blk < 5632) {
    in = wa; out = wab; base = blk - 4096;
  } else {
    in = wo; out = wob; base = blk - 5632;
  }
  long i = (base * 256 + threadIdx.x) * 8;
  u32 u[8];
#pragma unroll
  for (int j = 0; j < 8; j++) {
    u32 b = __float_as_uint(in[i + j]);
    u[j] = (b + 0x7fffu + ((b >> 16) & 1u)) >> 16;
  }
  u32x4 o;
  o[0] = u[0] | (u[1] << 16);
  o[1] = u[2] | (u[3] << 16);
  o[2] = u[4] | (u[5] << 16);
  o[3] = u[6] | (u[7] << 16);
  *(u32x4*)(out + i) = o;
}

// ---------------- 128x128 GEMM core, 3-slot K=32 ring (R11, kept) -----------
// Ring ledger: prologue stages hs 0,1; iter j stages hs j+2 into slot
// (j+2)%3; boundary vmcnt(4) drains stage(j) only, stage(j+1) in flight [T4].
// Chunk swizzle [T2]: phys chunk p at row r holds logical p ^ ((r>>1)&3),
// pre-applied to the global source; frag reads <=2-way banked (free).
__device__ __forceinline__ void gemm_core_r3(const u16* __restrict__ A,
                                             const u16* __restrict__ B,
                                             int m0, int n0, u16* lds,
                                             f32x4 acc[4][4]) {
  const int K = 1024;
  int t = threadIdx.x, lane = t & 63, w = t >> 6;  // 4 waves
  int quad = lane >> 4, l16 = lane & 15;
  int wm = (w >> 1) * 64, wn = (w & 1) * 64;
  int lrow = lane >> 2;
  int lchunk = (lane & 3) ^ ((lane >> 3) & 3);  // pre-swizzled source chunk
  const u16* Ag0 = A + (long)(m0 + w * 16 + lrow) * K + lchunk * 8;
  const u16* Ag1 = A + (long)(m0 + 64 + w * 16 + lrow) * K + lchunk * 8;
  const u16* Bg0 = B + (long)(n0 + w * 16 + lrow) * K + lchunk * 8;
  const u16* Bg1 = B + (long)(n0 + 64 + w * 16 + lrow) * K + lchunk * 8;
  u16* Ad0 = lds + (w * 16) * 32;
  u16* Ad1 = lds + (64 + w * 16) * 32;
  u16* Bd0 = lds + 4096 + (w * 16) * 32;
  u16* Bd1 = lds + 4096 + (64 + w * 16) * 32;
  int rk = (quad ^ ((l16 >> 1) & 3)) * 8;
  const u16* aR = lds + (wm + l16) * 32 + rk;         // + tm*512 + slot*8192
  const u16* bR = lds + 4096 + (wn + l16) * 32 + rk;  // + tn*512 + slot*8192

#define STG_R3(kk, ss)                            \
  do {                                            \
    gload_lds16(Ag0 + (kk), Ad0 + (ss) * 8192);   \
    gload_lds16(Ag1 + (kk), Ad1 + (ss) * 8192);   \
    gload_lds16(Bg0 + (kk), Bd0 + (ss) * 8192);   \
    gload_lds16(Bg1 + (kk), Bd1 + (ss) * 8192);   \
  } while (0)

#define BOUND_R3                                     \
  __builtin_amdgcn_sched_barrier(0);                 \
  asm volatile("s_waitcnt vmcnt(4)" ::: "memory");   \
  __builtin_amdgcn_s_barrier();                      \
  __builtin_amdgcn_sched_barrier(0)

#define CMP_R3(ss)                                                   \
  do {                                                               \
    bf16x8 a_[4], b_[4];                                             \
    _Pragma("unroll") for (int tm = 0; tm < 4; tm++)                 \
        a_[tm] = *(const bf16x8*)(aR + (ss) * 8192 + tm * 512);      \
    _Pragma("unroll") for (int tn = 0; tn < 4; tn++)                 \
        b_[tn] = *(const bf16x8*)(bR + (ss) * 8192 + tn * 512);      \
    asm volatile("s_waitcnt lgkmcnt(0)" ::: "memory");               \
    __builtin_amdgcn_sched_barrier(0);                               \
    __builtin_amdgcn_s_setprio(1);                                   \
    _Pragma("unroll") for (int tm = 0; tm < 4; tm++)                 \
        _Pragma("unroll") for (int tn = 0; tn < 4; tn++)             \
            acc[tm][tn] = mfma32(a_[tm], b_[tn], acc[tm][tn]);       \
    __builtin_amdgcn_s_setprio(0);                                   \
    __builtin_amdgcn_sched_barrier(0);                               \
  } while (0)

  STG_R3(0, 0);
  STG_R3(32, 1);
  for (int hb = 0; hb < 30; hb += 3) {
    BOUND_R3;
    STG_R3(((hb + 2) & 31) * 32, 2);
    CMP_R3(0);
    BOUND_R3;
    STG_R3(((hb + 3) & 31) * 32, 0);
    CMP_R3(1);
    BOUND_R3;
    STG_R3(((hb + 4) & 31) * 32, 1);
    CMP_R3(2);
  }
  BOUND_R3;
  STG_R3(0, 2);  // wrapped (dead) staging keeps vmcnt uniform
  CMP_R3(0);
  BOUND_R3;
  CMP_R3(1);
  asm volatile("s_waitcnt vmcnt(0)" ::: "memory");  // drain before LDS reuse
#undef STG_R3
#undef BOUND_R3
#undef CMP_R3
}

// ---------------- GEMM1 (SWAPPED): kqv^T = W_attn @ x^T, scatter K/Q/Vt -----
// Epilogue R8-verbatim (direct scatter; via-LDS port pending R12 result).
#define QSCALE 0.1803368801f
__global__ __launch_bounds__(256, 3) void gemm_qkv(const u16* __restrict__ A,
                                                   const u16* __restrict__ B,
                                                   const float* __restrict__ bias,
                                                   u16* __restrict__ Kg,
                                                   u16* __restrict__ Qg,
                                                   u16* __restrict__ Vg) {
  __shared__ __align__(16) u16 ring[3 * 8192];  // 48KB: 3 x (A 8KB | B 8KB)
  int m0 = blockIdx.y * 128, n0 = blockIdx.x * 128;  // m=feature, n=token
  f32x4 acc[4][4];
#pragma unroll
  for (int i = 0; i < 4; i++)
#pragma unroll
    for (int j = 0; j < 4; j++) acc[i][j] = (f32x4)0.0f;
  gemm_core_r3(A, B, m0, n0, ring, acc);

  int t = threadIdx.x, lane = t & 63, w = t >> 6;
  int quad = lane >> 4, l16 = lane & 15;
  int wm = (w >> 1) * 64, wn = (w & 1) * 64;
  int which = m0 >> 10;  // 0=K,1=Q,2=V -- uniform for the whole block
#pragma unroll
  for (int tm = 0; tm < 4; tm++) {
    int m = m0 + wm + tm * 16 + quad * 4;  // feature e (r spans m..m+3)
    int h = (m >> 6) & 15, d0 = m & 63;
    f32x4 b4 = *(const f32x4*)&bias[m];
#pragma unroll
    for (int tn = 0; tn < 4; tn++) {
      int n = n0 + wn + tn * 16 + l16;  // token
      int b = n >> 11, s = n & 2047;
      long bh = (long)b * 16 + h;
      if (which == 0) {
        u32x2 pk;
        pk[0] = pk2bf(acc[tm][tn][0] + b4[0], acc[tm][tn][1] + b4[1]);
        pk[1] = pk2bf(acc[tm][tn][2] + b4[2], acc[tm][tn][3] + b4[3]);
        *(u32x2*)&Kg[(bh * 2048 + s) * 64 + d0] = pk;
      } else if (which == 1) {
        u32x2 pk;
        pk[0] = pk2bf((acc[tm][tn][0] + b4[0]) * QSCALE,
                      (acc[tm][tn][1] + b4[1]) * QSCALE);
        pk[1] = pk2bf((acc[tm][tn][2] + b4[2]) * QSCALE,
                      (acc[tm][tn][3] + b4[3]) * QSCALE);
        *(u32x2*)&Qg[(bh * 2048 + s) * 64 + d0] = pk;
      } else {
#pragma unroll
        for (int r = 0; r < 4; r++)
          Vg[(bh * 64 + d0 + r) * 2048 + s] = f2bf(acc[tm][tn][r] + b4[r]);
      }
    }
  }
}

// ---------------- GEMM2 (SWAPPED): out^T = W_out @ y^T (fp32 out) -----------
// R12: VIA-LDS COALESCED STORE. The direct store was 16B/lane at 4KB lane
// stride -- every f32x4 store scattered 64 lanes over 64 cache lines (~8x
// transaction inflation on 32MB of output). Now: 2 passes of 64 tokens;
// writer waves (wn==p*64) stage acc into the free 48KB ring as fp32
// [token][feature] with 16B-granule XOR swizzle (phys = g ^ (token&15),
// <=2-way banks = free); all waves read back with lanes owning CONTIGUOUS
// features -> 512B-per-token coalesced f32x4 stores. Bias folded as one
// f32x4 load per thread. Same adds, same order -> bit-identical output.
__global__ __launch_bounds__(256, 3) void gemm_out(const u16* __restrict__ A,
                                                   const u16* __restrict__ B,
                                                   const float* __restrict__ bias,
                                                   float* __restrict__ out) {
  __shared__ __align__(16) u16 ring[3 * 8192];  // 48KB
  int m0 = blockIdx.y * 128, n0 = blockIdx.x * 128;  // m=feature, n=token
  f32x4 acc[4][4];
#pragma unroll
  for (int i = 0; i < 4; i++)
#pragma unroll
    for (int j = 0; j < 4; j++) acc[i][j] = (f32x4)0.0f;
  gemm_core_r3(A, B, m0, n0, ring, acc);

  int t = threadIdx.x, lane = t & 63, w = t >> 6;
  int quad = lane >> 4, l16 = lane & 15;
  int gbase = (w >> 1) * 16;  // feature-granule base (wm/4)
  float* red = (float*)ring;  // 64 tokens x 128 features fp32 = 32KB
  int j = lane & 31, tok2 = lane >> 5;  // read-side: granule j, token pair
  f32x4 bias4 = *(const f32x4*)&bias[m0 + j * 4];
#pragma unroll
  for (int p = 0; p < 2; p++) {
    __syncthreads();
    if ((w & 1) == p) {
      // writer: token t' = tn*16+l16 (t'&15 == l16), granule g = gbase+tm*4+quad
#pragma unroll
      for (int tm = 0; tm < 4; tm++)
#pragma unroll
        for (int tn = 0; tn < 4; tn++) {
          int tloc = tn * 16 + l16;
          int g = gbase + tm * 4 + quad;
          *(f32x4*)&red[tloc * 128 + (g ^ l16) * 4] = acc[tm][tn];
        }
    }
    __syncthreads();
    // reader/storer: wave w owns tokens w*16 .. w*16+15; lanes own features
#pragma unroll
    for (int i = 0; i < 8; i++) {
      int tloc = w * 16 + i * 2 + tok2;
      f32x4 v = *(const f32x4*)&red[tloc * 128 + (j ^ (tloc & 15)) * 4];
      v = v + bias4;
      *(f32x4*)&out[(long)(n0 + p * 64 + tloc) * 1024 + m0 + j * 4] = v;
    }
  }
}

// ---------------- flash attention (R8 core + R12 XCD-coherent grid) ---------
// R12: grid axes SWAPPED to (64 bh, 8 qblock). Old (8,64) gave linear ID =
// qb + bh*8 -> XCD = qb%8: the 8 q-blocks sharing one head's 512KB K/V
// landed on 8 DIFFERENT XCDs -> 8x K/V fetch (measured FETCH 139MB vs 48
// ideal). New: ID = bh + qb*64 -> XCD = bh%8: all sharers co-located; K/V
// fetched once into that XCD's L2 (per-XCD working set 4bh x 512KB = 2MB
// < 4MB L2). [T1 mechanism: neighbor blocks share operand panels.]
// Core unchanged: 512 thr (8 waves x 32 q), 2 blocks/CU, P granule-XOR
// conflict-free (measured 0), 28 MFMA/visit, ones-MFMA denominator.
#define SYNC                                       \
  __builtin_amdgcn_sched_barrier(0);               \
  asm volatile("s_waitcnt vmcnt(0)" ::: "memory"); \
  __builtin_amdgcn_s_barrier();                    \
  __builtin_amdgcn_sched_barrier(0)

#define STAGE_KV(tt, bb)                                      \
  do {                                                        \
    gload_lds16(Kst + (long)(tt)*4096, &Ks[bb][w * 8 * 64]);  \
    gload_lds16(Vst + (tt)*64, &Vs[bb][w * 8 * 64]);          \
  } while (0)

#define COMPUTE(bb)                                                            \
  do {                                                                         \
    bf16x8 pf_[2][2];                                                          \
    _Pragma("unroll") for (int tq = 0; tq < 2; tq++) {                         \
      f32x4 s_[4];                                                             \
      __builtin_amdgcn_s_setprio(1);                                           \
      _Pragma("unroll") for (int tn = 0; tn < 4; tn++) {                       \
        bf16x8 kf0 = *(const bf16x8*)(kL0 + (bb)*4096 + tn * 1024);            \
        bf16x8 kf1 = *(const bf16x8*)(kL1 + (bb)*4096 + tn * 1024);            \
        s_[tn] = __builtin_amdgcn_mfma_f32_16x16x32_bf16(kf0, qf[tq][0], Z,    \
                                                         0, 0, 0);             \
        s_[tn] = __builtin_amdgcn_mfma_f32_16x16x32_bf16(kf1, qf[tq][1],       \
                                                         s_[tn], 0, 0, 0);     \
      }                                                                        \
      __builtin_amdgcn_s_setprio(0);                                           \
      _Pragma("unroll") for (int tn = 0; tn < 4; tn++) {                       \
        float e0 = fexp2(s_[tn][0]);                                           \
        float e1 = fexp2(s_[tn][1]);                                           \
        float e2 = fexp2(s_[tn][2]);                                           \
        float e3 = fexp2(s_[tn][3]);                                           \
        u32x2 pk;                                                              \
        pk[0] = pk2bf(e0, e1);                                                 \
        pk[1] = pk2bf(e2, e3);                                                 \
        *(u32x2*)(pW + tq * 1024 + woff[tn]) = pk;                             \
      }                                                                        \
    }                                                                          \
    _Pragma("unroll") for (int ks = 0; ks < 2; ks++)                           \
        _Pragma("unroll") for (int tq = 0; tq < 2; tq++) {                     \
      u32x2 lo = *(const u32x2*)(pR + tq * 1024 + prlo[ks]);                   \
      u32x2 hi = *(const u32x2*)(pR + tq * 1024 + prhi[ks]);                   \
      u32x4 cc;                                                                \
      cc[0] = lo[0];                                                           \
      cc[1] = lo[1];                                                           \
      cc[2] = hi[0];                                                           \
      cc[3] = hi[1];                                                           \
      pf_[tq][ks] = __builtin_bit_cast(bf16x8, cc);                            \
    }                                                                          \
    __builtin_amdgcn_s_setprio(1);                                             \
    _Pragma("unroll") for (int ks = 0; ks < 2; ks++) {                         \
      acc_sum[0] = __builtin_amdgcn_mfma_f32_16x16x32_bf16(ONES, pf_[0][ks],   \
                                                           acc_sum[0], 0, 0, 0); \
      acc_sum[1] = __builtin_amdgcn_mfma_f32_16x16x32_bf16(ONES, pf_[1][ks],   \
                                                           acc_sum[1], 0, 0, 0); \
      _Pragma("unroll") for (int dt = 0; dt < 4; dt++) {                       \
        bf16x8 vf = *(const bf16x8*)(vL[ks] + (bb)*4096 + dt * 1024);          \
        acc[dt][0] = __builtin_amdgcn_mfma_f32_16x16x32_bf16(vf, pf_[0][ks],   \
                                                             acc[dt][0], 0, 0, 0); \
        acc[dt][1] = __builtin_amdgcn_mfma_f32_16x16x32_bf16(vf, pf_[1][ks],   \
                                                             acc[dt][1], 0, 0, 0); \
      }                                                                        \
    }                                                                          \
    __builtin_amdgcn_s_setprio(0);                                             \
  } while (0)

__global__ __launch_bounds__(512, 4) void attn_kernel(const u16* __restrict__ Qg,
                                                      const u16* __restrict__ Kg,
                                                      const u16* __restrict__ Vg,
                                                      u16* __restrict__ Y) {
  __shared__ __align__(16) u16 Ks[2][64 * 64];     // [buf][kv][d] XOR-swizzled
  __shared__ __align__(16) u16 Vs[2][64 * 64];     // [buf][d][kv] XOR-swizzled
  __shared__ __align__(16) u16 Ps[8 * 32 * 64];    // per-wave [q][kv] granule-swz
  int t = threadIdx.x, lane = t & 63, w = t >> 6;  // 8 waves
  int quad = lane >> 4, l16 = lane & 15;
  int bh = blockIdx.x;                      // R12: bh on x -> XCD = bh%8
  int q0 = blockIdx.y * 256 + w * 32;       // q-block on y
  int lr = lane >> 3, lc = lane & 7, cg = lc ^ lr;
  int swz = l16 & 7;
  u16* Pw = Ps + w * 2048;

  // Q fragments (MFMA B-operand), loaded once: qf[tq][ks]
  bf16x8 qf[2][2];
#pragma unroll
  for (int tq = 0; tq < 2; tq++) {
    const u16* qp = Qg + ((long)bh * 2048 + q0 + tq * 16 + l16) * 64;
    qf[tq][0] = *(const bf16x8*)(qp + quad * 8);
    qf[tq][1] = *(const bf16x8*)(qp + 32 + quad * 8);
  }

  const f32x4 Z = {0.0f, 0.0f, 0.0f, 0.0f};  // hoisted zero C-operand
  const bf16x8 ONES = mk_ones8();            // bf16 1.0 x8 (denominator MFMA)

  f32x4 acc[4][2];   // [dt d][tq q]  out^T: row=d, col=q
  f32x4 acc_sum[2];  // softmax denominators via ones-MFMA (all rows equal)
#pragma unroll
  for (int dt = 0; dt < 4; dt++)
#pragma unroll
    for (int tq = 0; tq < 2; tq++) acc[dt][tq] = (f32x4)0.0f;
  acc_sum[0] = (f32x4)0.0f;
  acc_sum[1] = (f32x4)0.0f;

  // loop-invariant LDS lane pointers (compile-time immediates added per use)
  const u16* kL0 = &Ks[0][l16 * 64 + (quad ^ swz) * 8];        // ks=0 chunk
  const u16* kL1 = &Ks[0][l16 * 64 + ((4 + quad) ^ swz) * 8];  // ks=1 chunk
  const u16* vL[2] = {&Vs[0][l16 * 64 + (quad ^ swz) * 8],
                      &Vs[0][l16 * 64 + ((4 + quad) ^ swz) * 8]};
  u16* pW = Pw + l16 * 64;
  const u16* pR = Pw + l16 * 64;
  // P granule swizzle: 8B granule g_phys = g_log ^ l16 (full 4-bit row key)
  int woff[4], prlo[2], prhi[2];
#pragma unroll
  for (int tn = 0; tn < 4; tn++) woff[tn] = ((tn * 4 + quad) ^ l16) * 4;
#pragma unroll
  for (int ks = 0; ks < 2; ks++) {
    prlo[ks] = ((ks * 8 + quad * 2) ^ l16) * 4;
    prhi[ks] = ((ks * 8 + quad * 2 + 1) ^ l16) * 4;
  }

  // staging base pointers: wave w stages rows w*8..w*8+7 of each tile
  const u16* Kst = Kg + ((long)bh * 2048 + w * 8 + lr) * 64 + cg * 8;   // +tt*4096
  const u16* Vst = Vg + ((long)(bh * 64 + w * 8 + lr)) * 2048 + cg * 8; // +tt*64

  STAGE_KV(0, 0);
  for (int tt = 0; tt < 30; tt += 2) {
    SYNC;
    STAGE_KV(tt + 1, 1);
    COMPUTE(0);
    SYNC;
    STAGE_KV(tt + 2, 0);
    COMPUTE(1);
  }
  SYNC;
  STAGE_KV(31, 1);
  COMPUTE(0);
  SYNC;
  COMPUTE(1);

  // epilogue: out^T row=d=dt*16+quad*4+r, col=q=tq*16+l16.
  // acc_sum rows all identical (ones-A) => full denominator in every reg.
  int b = bh >> 4, h = bh & 15;
#pragma unroll
  for (int tq = 0; tq < 2; tq++) {
    float inv = 1.0f / acc_sum[tq][0];
    long row = (long)b * 2048 + q0 + tq * 16 + l16;
#pragma unroll
    for (int dt = 0; dt < 4; dt++) {
      u32x2 pk;
      pk[0] = pk2bf(acc[dt][tq][0] * inv, acc[dt][tq][1] * inv);
      pk[1] = pk2bf(acc[dt][tq][2] * inv, acc[dt][tq][3] * inv);
      *(u32x2*)&Y[row * 1024 + h * 64 + dt * 16 + quad * 4] = pk;
    }
  }
}

// ---------------- launch ----------------------------------------------------
extern "C" void kernel_launch(void* const* d_in, const int* in_sizes, int n_in,
                              void* d_out, int out_size, void* d_ws, size_t ws_size,
                              hipStream_t stream) {
  const float* x = (const float*)d_in[0];       // (4,2048,1024)
  const float* W_attn = (const float*)d_in[1];  // (3072,1024)
  const float* b_attn = (const float*)d_in[2];  // (3072,)
  const float* W_out = (const float*)d_in[3];   // (1024,1024)
  const float* b_out = (const float*)d_in[4];   // (1024,)
  float* out = (float*)d_out;                   // (4,2048,1024) fp32

  char* ws = (char*)d_ws;
  u16* xb = (u16*)ws;                             // 8192*1024 bf16 = 16 MB
  u16* Wab = (u16*)(ws + 16777216);               // 3072*1024 = 6 MB
  u16* Wob = (u16*)(ws + 16777216 + 6291456);     // 1024*1024 = 2 MB
  u16* Kg = (u16*)(ws + 25165824);                // (b,h,s,d) 16 MB
  u16* Qg = Kg + 8388608;                         // (b,h,s,d) pre-scaled 16 MB
  u16* Vg = Qg + 8388608;                         // (b,h,d,s) 16 MB
  u16* Yb = xb;  // alias: x no longer needed after GEMM1

  cvt_all<<<6144, 256, 0, stream>>>(x, W_attn, W_out, xb, Wab, Wob);

  // SWAPPED gemms: A = weights (feature rows), B = activations (token rows)
  gemm_qkv<<<dim3(64, 24), 256, 0, stream>>>(Wab, xb, b_attn, Kg, Qg, Vg);
  attn_kernel<<<dim3(64, 8), 512, 0, stream>>>(Qg, Kg, Vg, Yb);  // bh-major
  gemm_out<<<dim3(64, 8), 256, 0, stream>>>(Wob, Yb, b_out, out);
}